// Round 10
// baseline (134.306 us; speedup 1.0000x reference)
//
#include <hip/hip_runtime.h>
#include <math.h>

typedef float v2f __attribute__((ext_vector_type(2)));

#define NSUP 512
#define DLAT 128
#define DHID 512
#define DIN  64
#define BR   16
#define NTILE 256   // 4096 / 16

// ---------------- prep: transposes + packs + planar support trig + norms ----------------
__global__ __launch_bounds__(512) void prep_kernel(
    const float* __restrict__ x, const float* __restrict__ W1, const float* __restrict__ W2,
    const float* __restrict__ support,
    float* __restrict__ W1T, float* __restrict__ W2T, float* __restrict__ xpack,
    float* __restrict__ scS, float* __restrict__ scC, float* __restrict__ scN,
    float* __restrict__ sn2)
{
    int idx = blockIdx.x * 512 + threadIdx.x;          // 512 x 512 = 262144
    {   // xpack[t][k][r] = x[t*16+r][k]   (writes coalesced)
        int t = idx >> 10, rem = idx & 1023, k = rem >> 4, r = rem & 15;
        xpack[idx] = x[((t << 4) | r) * DIN + k];
    }
    if (idx < DHID * DIN) {                 // W1 [512][64] -> W1T [64][512]
        int c = idx / DIN, k = idx % DIN;
        W1T[k * DHID + c] = W1[idx];
    }
    if (idx < DLAT * DHID) {
        int j = idx / DHID, k = idx % DHID;             // W2 -> W2T
        W2T[k * DLAT + j] = W2[idx];
        int s = idx & (NSUP - 1), i = idx >> 9;         // planar [i][s], writes coalesced
        float v = support[s * DLAT + i];
        scS[idx] = v;
        scC[idx] = cosf(0.5f * v);
        scN[idx] = sinf(0.5f * v);
    }
    if (idx < NSUP) {                       // ||s||^2 via float4
        const float4* sp = (const float4*)(support + idx * DLAT);
        float acc = 0.f;
        #pragma unroll 8
        for (int i4 = 0; i4 < DLAT / 4; i4++) {
            float4 v = sp[i4];
            acc = fmaf(v.x, v.x, fmaf(v.y, v.y, fmaf(v.z, v.z, fmaf(v.w, v.w, acc))));
        }
        sn2[idx] = acc;
    }
}

// ---------------- GEMM1: h = tanh(x @ W1^T + b1)  (s_load broadcast path) ----------------
__global__ __launch_bounds__(512) void gemm1_kernel(
    const float* __restrict__ W1T, const float* __restrict__ b1,
    const float* __restrict__ xpack, float* __restrict__ hpack)
{
    __shared__ float sh[DHID][17];                           // 34.8 KB
    const int t = blockIdx.x;
    const int c = threadIdx.x;
    const float* __restrict__ xr = xpack + t * (DIN * BR);   // uniform base -> s_load

    v2f acc[8];
    #pragma unroll
    for (int q = 0; q < 8; q++) acc[q] = (v2f)(0.f);

    for (int k = 0; k < DIN; k++) {
        float w = W1T[k * DHID + c];
        v2f wv = {w, w};
        const float* xk = xr + k * BR;                       // uniform -> s_load_dwordx16
        #pragma unroll
        for (int q = 0; q < 8; q++) {
            v2f xv = {xk[2 * q], xk[2 * q + 1]};
            acc[q] = __builtin_elementwise_fma(xv, wv, acc[q]);
        }
    }
    float bb = b1[c];
    #pragma unroll
    for (int q = 0; q < 8; q++) {
        sh[c][2 * q]     = tanhf(acc[q].x + bb);
        sh[c][2 * q + 1] = tanhf(acc[q].y + bb);
    }
    __syncthreads();
    float4* hp = (float4*)(hpack + t * (DHID * BR));
    #pragma unroll
    for (int w = threadIdx.x; w < DHID * BR / 4; w += 512) {
        int cc = w >> 2, r0 = (w & 3) * 4;
        hp[w] = make_float4(sh[cc][r0], sh[cc][r0 + 1], sh[cc][r0 + 2], sh[cc][r0 + 3]);
    }
}

// ---------------- GEMM2: latent + trig -> rowpack [t8][i][r8] = float4{l,a,b,0} ----------------
__global__ __launch_bounds__(1024) void gemm2_kernel(
    const float* __restrict__ W2T, const float* __restrict__ b2,
    const float* __restrict__ hpack, float4* __restrict__ rowpack4, float* __restrict__ ln2s)
{
    __shared__ float part[8][DLAT][17];    // 69632 B
    __shared__ float tbuf[DLAT][49];       // 25088 B: [j][rp*6] = {l0,l1,a0,a1,b0,b1}
    __shared__ float l2red[16][2];

    const int t = blockIdx.x;
    const int j = threadIdx.x & (DLAT - 1);
    const int g = __builtin_amdgcn_readfirstlane(threadIdx.x >> 7);   // wave-uniform
    const float* __restrict__ hrow = hpack + t * (DHID * BR);

    v2f acc[8];
    #pragma unroll
    for (int q = 0; q < 8; q++) acc[q] = (v2f)(0.f);

    for (int kk = 0; kk < 64; kk++) {
        int k = g * 64 + kk;
        float w = W2T[k * DLAT + j];
        v2f wv = {w, w};
        const float* hk = hrow + k * BR;               // uniform -> s_load_dwordx16
        #pragma unroll
        for (int q = 0; q < 8; q++) {
            v2f hv = {hk[2 * q], hk[2 * q + 1]};
            acc[q] = __builtin_elementwise_fma(hv, wv, acc[q]);
        }
    }
    #pragma unroll
    for (int q = 0; q < 8; q++) {
        part[g][j][2 * q]     = acc[q].x;
        part[g][j][2 * q + 1] = acc[q].y;
    }
    __syncthreads();

    const int rp = g;                                   // row-pair 0..7, rows 2rp, 2rp+1
    float s0 = 0.f, s1 = 0.f;
    #pragma unroll
    for (int g2 = 0; g2 < 8; g2++) {
        s0 += part[g2][j][2 * rp];
        s1 += part[g2][j][2 * rp + 1];
    }
    float bb = b2[j];
    float l0 = s0 + bb, l1 = s1 + bb;

    tbuf[j][rp * 6 + 0] = l0;
    tbuf[j][rp * 6 + 1] = l1;
    tbuf[j][rp * 6 + 2] = cosf(0.5f * l0);
    tbuf[j][rp * 6 + 3] = cosf(0.5f * l1);
    tbuf[j][rp * 6 + 4] = sinf(0.5f * l0);
    tbuf[j][rp * 6 + 5] = sinf(0.5f * l1);

    // ||l||^2 per row
    const int wv = threadIdx.x >> 6;
    float v0 = l0 * l0, v1 = l1 * l1;
    for (int off = 32; off; off >>= 1) { v0 += __shfl_down(v0, off); v1 += __shfl_down(v1, off); }
    if ((threadIdx.x & 63) == 0) { l2red[wv][0] = v0; l2red[wv][1] = v1; }
    __syncthreads();

    if (threadIdx.x < BR) {
        int r = threadIdx.x, p = r >> 1, sel = r & 1;
        ln2s[t * BR + r] = l2red[2 * p][sel] + l2red[2 * p + 1][sel];
    }
    // coalesced rowpack store: 2048 float4 per tile -> [t8][i][r8]
    #pragma unroll
    for (int w = threadIdx.x; w < 2048; w += 1024) {
        int t8h = w >> 10, rem = w & 1023, jj = rem >> 3, r8 = rem & 7;
        int row = t8h * 8 + r8, rpx = row >> 1, o = row & 1;
        rowpack4[(t * 2 + t8h) * 1024 + rem] =
            make_float4(tbuf[jj][rpx * 6 + o], tbuf[jj][rpx * 6 + 2 + o],
                        tbuf[jj][rpx * 6 + 4 + o], 0.f);
    }
}

// ---------------- stage B: zero-redundancy. grid 512 row-octiles. ----------------
// block 512 thr = 8 waves; wave w = row t8*8+w; lane = sups lane*8..lane*8+7 (all 512/block).
__global__ __launch_bounds__(512, 4) void kernelB(
    const float* __restrict__ scS, const float* __restrict__ scC, const float* __restrict__ scN,
    const float* __restrict__ sn2, const float* __restrict__ wts,
    const float4* __restrict__ rowpack4, const float* __restrict__ ln2s,
    float* __restrict__ out)
{
    __shared__ float4 tile4[DLAT * 8];   // 16 KB: [i][r8] = {l,a,b,0}

    const int t8   = blockIdx.x;
    const int tid  = threadIdx.x;
    const int lane = tid & 63;
    const int w    = __builtin_amdgcn_readfirstlane(tid >> 6);  // wave = row index

    // ---- stage row tile: 1024 float4, coalesced ----
    {
        const float4* src = rowpack4 + t8 * 1024;
        tile4[tid]       = src[tid];
        tile4[tid + 512] = src[tid + 512];
    }
    __syncthreads();

    float dot[8]  = {0.f, 0.f, 0.f, 0.f, 0.f, 0.f, 0.f, 0.f};
    float prod[8] = {1.f, 1.f, 1.f, 1.f, 1.f, 1.f, 1.f, 1.f};

    const int l2o = lane << 1;   // float4 index of this lane's 8 sups

    #define COMPUTE(S0, S1, C0, C1, N0, N1, RW)                                   \
    {                                                                             \
        float sv[8] = {S0.x, S0.y, S0.z, S0.w, S1.x, S1.y, S1.z, S1.w};           \
        float cv[8] = {C0.x, C0.y, C0.z, C0.w, C1.x, C1.y, C1.z, C1.w};           \
        float nv[8] = {N0.x, N0.y, N0.z, N0.w, N1.x, N1.y, N1.z, N1.w};           \
        _Pragma("unroll")                                                         \
        for (int k = 0; k < 8; k++) {                                             \
            dot[k] = fmaf(sv[k], RW.x, dot[k]);                                   \
            float tt = fmaf(nv[k], RW.z, cv[k] * RW.y);                           \
            prod[k] *= tt;                                                        \
        }                                                                         \
    }

    for (int i = 0; i < DLAT; i += 2) {
        const float4* pS0 = (const float4*)(scS + i * NSUP) + l2o;
        const float4* pC0 = (const float4*)(scC + i * NSUP) + l2o;
        const float4* pN0 = (const float4*)(scN + i * NSUP) + l2o;
        const float4* pS1 = (const float4*)(scS + (i + 1) * NSUP) + l2o;
        const float4* pC1 = (const float4*)(scC + (i + 1) * NSUP) + l2o;
        const float4* pN1 = (const float4*)(scN + (i + 1) * NSUP) + l2o;
        float4 sA0 = pS0[0], sA1 = pS0[1];
        float4 cA0 = pC0[0], cA1 = pC0[1];
        float4 nA0 = pN0[0], nA1 = pN0[1];
        float4 sB0 = pS1[0], sB1 = pS1[1];
        float4 cB0 = pC1[0], cB1 = pC1[1];
        float4 nB0 = pN1[0], nB1 = pN1[1];
        float4 r0 = tile4[i * 8 + w];              // uniform -> LDS broadcast b128
        float4 r1 = tile4[(i + 1) * 8 + w];
        COMPUTE(sA0, sA1, cA0, cA1, nA0, nA1, r0)
        COMPUTE(sB0, sB1, cB0, cB1, nB0, nB1, r1)
    }
    #undef COMPUTE

    // ---- epilogue: kernels, weight, full in-block reduction (this wave owns its row) ----
    float ln2v = ln2s[t8 * 8 + w];                 // wave-uniform scalar
    const float4* snp = (const float4*)(sn2) + l2o;
    const float4* wtp = (const float4*)(wts) + l2o;
    float4 sn0 = snp[0], sn1 = snp[1];
    float4 wt0 = wtp[0], wt1 = wtp[1];
    float snv[8] = {sn0.x, sn0.y, sn0.z, sn0.w, sn1.x, sn1.y, sn1.z, sn1.w};
    float wtv[8] = {wt0.x, wt0.y, wt0.z, wt0.w, wt1.x, wt1.y, wt1.z, wt1.w};

    float acc = 0.f;
    #pragma unroll
    for (int k = 0; k < 8; k++) {
        float sq = ln2v + snv[k] - 2.f * dot[k];
        acc += (0.5f * __expf(-sq) + 0.5f * prod[k] * prod[k]) * wtv[k];
    }
    for (int off = 32; off; off >>= 1) acc += __shfl_down(acc, off);
    if (lane == 0) out[t8 * 8 + w] = acc;
}

// ---------------- launch ----------------
extern "C" void kernel_launch(void* const* d_in, const int* in_sizes, int n_in,
                              void* d_out, int out_size, void* d_ws, size_t ws_size,
                              hipStream_t stream) {
    const float* x       = (const float*)d_in[0];
    const float* W1      = (const float*)d_in[1];
    const float* b1      = (const float*)d_in[2];
    const float* W2      = (const float*)d_in[3];
    const float* b2      = (const float*)d_in[4];
    const float* support = (const float*)d_in[5];
    const float* wts     = (const float*)d_in[6];
    float* out = (float*)d_out;

    float* ws      = (float*)d_ws;
    float* W1T     = ws;                        // 32768
    float* W2T     = W1T + 32768;               // 65536
    float* xpack   = W2T + 65536;               // 262144
    float* hpack   = xpack + 262144;            // 2097152   (16B-aligned offset)
    float* rowpack = hpack + 2097152;           // 2097152 floats = 524288 float4 (16B-aligned)
    float* ln2s    = rowpack + 2097152;         // 4096
    float* sn2     = ln2s + 4096;               // 512
    float* scS     = sn2 + 512;                 // 65536 (16B-aligned offset)
    float* scC     = scS + 65536;               // 65536
    float* scN     = scC + 65536;               // 65536

    prep_kernel <<<512,  512, 0, stream>>>(x, W1, W2, support, W1T, W2T, xpack,
                                           scS, scC, scN, sn2);
    gemm1_kernel<<<NTILE, 512, 0, stream>>>(W1T, b1, xpack, hpack);
    gemm2_kernel<<<NTILE, 1024, 0, stream>>>(W2T, b2, hpack, (float4*)rowpack, ln2s);
    kernelB     <<<512, 512, 0, stream>>>(scS, scC, scN, sn2, wts,
                                          (const float4*)rowpack, ln2s, out);
}

// Round 11
// 113.336 us; speedup vs baseline: 1.1850x; 1.1850x over previous
//
#include <hip/hip_runtime.h>
#include <math.h>

typedef float v2f __attribute__((ext_vector_type(2)));

#define NSUP 512
#define DLAT 128
#define DHID 512
#define DIN  64
#define BR   16
#define NTILE 256   // 4096 / 16

// ---------------- prep: transposes + packs + planar support trig + norms ----------------
__global__ __launch_bounds__(512) void prep_kernel(
    const float* __restrict__ x, const float* __restrict__ W1, const float* __restrict__ W2,
    const float* __restrict__ support,
    float* __restrict__ W1T, float* __restrict__ W2T, float* __restrict__ xpack,
    float* __restrict__ scS, float* __restrict__ scC, float* __restrict__ scN,
    float* __restrict__ sn2)
{
    int idx = blockIdx.x * 512 + threadIdx.x;          // 512 x 512 = 262144
    {   // xpack[t][k][r] = x[t*16+r][k]   (writes coalesced)
        int t = idx >> 10, rem = idx & 1023, k = rem >> 4, r = rem & 15;
        xpack[idx] = x[((t << 4) | r) * DIN + k];
    }
    if (idx < DHID * DIN) {                 // W1 [512][64] -> W1T [64][512]
        int c = idx / DIN, k = idx % DIN;
        W1T[k * DHID + c] = W1[idx];
    }
    if (idx < DLAT * DHID) {
        int j = idx / DHID, k = idx % DHID;             // W2 -> W2T
        W2T[k * DLAT + j] = W2[idx];
        int s = idx & (NSUP - 1), i = idx >> 9;         // planar [i][s], writes coalesced
        float v = support[s * DLAT + i];
        scS[idx] = v;
        scC[idx] = cosf(0.5f * v);
        scN[idx] = sinf(0.5f * v);
    }
    if (idx < NSUP) {                       // ||s||^2 via float4
        const float4* sp = (const float4*)(support + idx * DLAT);
        float acc = 0.f;
        #pragma unroll 8
        for (int i4 = 0; i4 < DLAT / 4; i4++) {
            float4 v = sp[i4];
            acc = fmaf(v.x, v.x, fmaf(v.y, v.y, fmaf(v.z, v.z, fmaf(v.w, v.w, acc))));
        }
        sn2[idx] = acc;
    }
}

// ---------------- GEMM1: h = tanh(x @ W1^T + b1)  (s_load broadcast path) ----------------
__global__ __launch_bounds__(512) void gemm1_kernel(
    const float* __restrict__ W1T, const float* __restrict__ b1,
    const float* __restrict__ xpack, float* __restrict__ hpack)
{
    __shared__ float sh[DHID][17];                           // 34.8 KB
    const int t = blockIdx.x;
    const int c = threadIdx.x;
    const float* __restrict__ xr = xpack + t * (DIN * BR);   // uniform base -> s_load

    v2f acc[8];
    #pragma unroll
    for (int q = 0; q < 8; q++) acc[q] = (v2f)(0.f);

    for (int k = 0; k < DIN; k++) {
        float w = W1T[k * DHID + c];
        v2f wv = {w, w};
        const float* xk = xr + k * BR;                       // uniform -> s_load_dwordx16
        #pragma unroll
        for (int q = 0; q < 8; q++) {
            v2f xv = {xk[2 * q], xk[2 * q + 1]};
            acc[q] = __builtin_elementwise_fma(xv, wv, acc[q]);
        }
    }
    float bb = b1[c];
    #pragma unroll
    for (int q = 0; q < 8; q++) {
        sh[c][2 * q]     = tanhf(acc[q].x + bb);
        sh[c][2 * q + 1] = tanhf(acc[q].y + bb);
    }
    __syncthreads();
    float4* hp = (float4*)(hpack + t * (DHID * BR));
    #pragma unroll
    for (int w = threadIdx.x; w < DHID * BR / 4; w += 512) {
        int cc = w >> 2, r0 = (w & 3) * 4;
        hp[w] = make_float4(sh[cc][r0], sh[cc][r0 + 1], sh[cc][r0 + 2], sh[cc][r0 + 3]);
    }
}

// ---------------- GEMM2: latent + trig -> rowpack [t][i][rgrp4][{l4|a4|b4}] ----------------
__global__ __launch_bounds__(1024) void gemm2_kernel(
    const float* __restrict__ W2T, const float* __restrict__ b2,
    const float* __restrict__ hpack, float4* __restrict__ rowpack4, float* __restrict__ ln2s)
{
    __shared__ float part[8][DLAT][17];    // 69632 B
    __shared__ float tbuf[DLAT][49];       // 25088 B: [j][rp*6] = {l0,l1,a0,a1,b0,b1}
    __shared__ float l2red[16][2];

    const int t = blockIdx.x;
    const int j = threadIdx.x & (DLAT - 1);
    const int g = __builtin_amdgcn_readfirstlane(threadIdx.x >> 7);   // wave-uniform
    const float* __restrict__ hrow = hpack + t * (DHID * BR);

    v2f acc[8];
    #pragma unroll
    for (int q = 0; q < 8; q++) acc[q] = (v2f)(0.f);

    for (int kk = 0; kk < 64; kk++) {
        int k = g * 64 + kk;
        float w = W2T[k * DLAT + j];
        v2f wv = {w, w};
        const float* hk = hrow + k * BR;               // uniform -> s_load_dwordx16
        #pragma unroll
        for (int q = 0; q < 8; q++) {
            v2f hv = {hk[2 * q], hk[2 * q + 1]};
            acc[q] = __builtin_elementwise_fma(hv, wv, acc[q]);
        }
    }
    #pragma unroll
    for (int q = 0; q < 8; q++) {
        part[g][j][2 * q]     = acc[q].x;
        part[g][j][2 * q + 1] = acc[q].y;
    }
    __syncthreads();

    const int rp = g;                                   // row-pair 0..7, rows 2rp, 2rp+1
    float s0 = 0.f, s1 = 0.f;
    #pragma unroll
    for (int g2 = 0; g2 < 8; g2++) {
        s0 += part[g2][j][2 * rp];
        s1 += part[g2][j][2 * rp + 1];
    }
    float bb = b2[j];
    float l0 = s0 + bb, l1 = s1 + bb;

    tbuf[j][rp * 6 + 0] = l0;
    tbuf[j][rp * 6 + 1] = l1;
    tbuf[j][rp * 6 + 2] = cosf(0.5f * l0);
    tbuf[j][rp * 6 + 3] = cosf(0.5f * l1);
    tbuf[j][rp * 6 + 4] = sinf(0.5f * l0);
    tbuf[j][rp * 6 + 5] = sinf(0.5f * l1);

    // ||l||^2 per row
    const int wv = threadIdx.x >> 6;
    float v0 = l0 * l0, v1 = l1 * l1;
    for (int off = 32; off; off >>= 1) { v0 += __shfl_down(v0, off); v1 += __shfl_down(v1, off); }
    if ((threadIdx.x & 63) == 0) { l2red[wv][0] = v0; l2red[wv][1] = v1; }
    __syncthreads();

    if (threadIdx.x < BR) {
        int r = threadIdx.x, p = r >> 1, sel = r & 1;
        ln2s[t * BR + r] = l2red[2 * p][sel] + l2red[2 * p + 1][sel];
    }
    // coalesced store: 1536 float4/tile -> [i][rg][pq]: float4 idx = i*12 + rg*3 + pq
    for (int w4 = threadIdx.x; w4 < 1536; w4 += 1024) {
        int i = w4 / 12, c = w4 % 12, rg = c / 3, pq = c % 3;
        float vals[4];
        #pragma unroll
        for (int k = 0; k < 4; k++) {
            int r = rg * 4 + k;
            vals[k] = tbuf[i][(r >> 1) * 6 + pq * 2 + (r & 1)];
        }
        rowpack4[t * 1536 + w4] = make_float4(vals[0], vals[1], vals[2], vals[3]);
    }
}

// ---------------- stage B: 2D register tile, disjoint wave sup-windows ----------------
// grid 256 (row-tiles of 16). block 512 = 8 waves; wave w owns sups [w*64, w*64+64).
// lane = rr*16+sl: 4x4 tile = rows rr*4..+3  x  sups w*64+sl*4..+3. Zero LDS main loop.
__global__ __launch_bounds__(512) void kernelB(
    const float* __restrict__ scS, const float* __restrict__ scC, const float* __restrict__ scN,
    const float* __restrict__ sn2, const float* __restrict__ wts,
    const float* __restrict__ rowpackB, const float* __restrict__ ln2s,
    float* __restrict__ out)
{
    __shared__ float part[8][BR];

    const int t    = blockIdx.x;
    const int tid  = threadIdx.x;
    const int lane = tid & 63;
    const int w    = __builtin_amdgcn_readfirstlane(tid >> 6);
    const int rr   = lane >> 4;          // row-quad 0..3
    const int sl   = lane & 15;          // sup-slot 0..15
    const int sb   = w * 64 + sl * 4;    // 4 consecutive sups

    const float* rp = rowpackB + t * (DLAT * 48) + rr * 12;   // [i][rgrp][{l4|a4|b4}]
    const float* pS = scS + sb;
    const float* pC = scC + sb;
    const float* pN = scN + sb;

    float dot[4][4], prod[4][4];
    #pragma unroll
    for (int r = 0; r < 4; r++)
        #pragma unroll
        for (int s = 0; s < 4; s++) { dot[r][s] = 0.f; prod[r][s] = 1.f; }

    #pragma unroll 2
    for (int i = 0; i < DLAT; i++) {
        float4 lq = *(const float4*)(rp + i * 48);        // rows: 4-addr, 16-lane aliased
        float4 aq = *(const float4*)(rp + i * 48 + 4);
        float4 bq = *(const float4*)(rp + i * 48 + 8);
        float4 s4 = *(const float4*)(pS + i * NSUP);      // sups: coalesced, 4-aliased
        float4 c4 = *(const float4*)(pC + i * NSUP);
        float4 n4 = *(const float4*)(pN + i * NSUP);
        float lv[4] = {lq.x, lq.y, lq.z, lq.w};
        float av[4] = {aq.x, aq.y, aq.z, aq.w};
        float bv[4] = {bq.x, bq.y, bq.z, bq.w};
        float sv[4] = {s4.x, s4.y, s4.z, s4.w};
        float cv[4] = {c4.x, c4.y, c4.z, c4.w};
        float nv[4] = {n4.x, n4.y, n4.z, n4.w};
        #pragma unroll
        for (int r = 0; r < 4; r++) {
            #pragma unroll
            for (int s = 0; s < 4; s++) {
                dot[r][s] = fmaf(lv[r], sv[s], dot[r][s]);
                float tt = fmaf(bv[r], nv[s], av[r] * cv[s]);
                prod[r][s] *= tt;
            }
        }
    }

    // ---- epilogue ----
    float4 snq = *(const float4*)(sn2 + sb);
    float4 wtq = *(const float4*)(wts + sb);
    float4 l2q = *(const float4*)(ln2s + t * BR + rr * 4);
    float snv[4] = {snq.x, snq.y, snq.z, snq.w};
    float wtv[4] = {wtq.x, wtq.y, wtq.z, wtq.w};
    float l2v[4] = {l2q.x, l2q.y, l2q.z, l2q.w};

    #pragma unroll
    for (int r = 0; r < 4; r++) {
        float acc = 0.f;
        #pragma unroll
        for (int s = 0; s < 4; s++) {
            float sq_ = l2v[r] + snv[s] - 2.f * dot[r][s];
            float p   = prod[r][s];
            acc += (0.5f * __expf(-sq_) + 0.5f * p * p) * wtv[s];
        }
        for (int off = 8; off; off >>= 1) acc += __shfl_down(acc, off);   // over 16 sl-lanes
        if (sl == 0) part[w][rr * 4 + r] = acc;
    }
    __syncthreads();
    if (tid < BR) {
        float o = 0.f;
        #pragma unroll
        for (int ww = 0; ww < 8; ww++) o += part[ww][tid];
        out[t * BR + tid] = o;
    }
}

// ---------------- launch ----------------
extern "C" void kernel_launch(void* const* d_in, const int* in_sizes, int n_in,
                              void* d_out, int out_size, void* d_ws, size_t ws_size,
                              hipStream_t stream) {
    const float* x       = (const float*)d_in[0];
    const float* W1      = (const float*)d_in[1];
    const float* b1      = (const float*)d_in[2];
    const float* W2      = (const float*)d_in[3];
    const float* b2      = (const float*)d_in[4];
    const float* support = (const float*)d_in[5];
    const float* wts     = (const float*)d_in[6];
    float* out = (float*)d_out;

    float* ws      = (float*)d_ws;
    float* W1T     = ws;                        // 32768
    float* W2T     = W1T + 32768;               // 65536
    float* xpack   = W2T + 65536;               // 262144
    float* hpack   = xpack + 262144;            // 2097152   (16B-aligned offset)
    float* rowpack = hpack + 2097152;           // 1572864   (16B-aligned offset)
    float* ln2s    = rowpack + 1572864;         // 4096
    float* sn2     = ln2s + 4096;               // 512
    float* scS     = sn2 + 512;                 // 65536 (16B-aligned offset)
    float* scC     = scS + 65536;               // 65536
    float* scN     = scC + 65536;               // 65536

    prep_kernel <<<512,  512, 0, stream>>>(x, W1, W2, support, W1T, W2T, xpack,
                                           scS, scC, scN, sn2);
    gemm1_kernel<<<NTILE, 512, 0, stream>>>(W1T, b1, xpack, hpack);
    gemm2_kernel<<<NTILE, 1024, 0, stream>>>(W2T, b2, hpack, (float4*)rowpack, ln2s);
    kernelB     <<<NTILE, 512, 0, stream>>>(scS, scC, scN, sn2, wts,
                                            rowpack, ln2s, out);
}